// Round 2
// baseline (752.468 us; speedup 1.0000x reference)
//
#include <hip/hip_runtime.h>
#include <hip/hip_bf16.h>

typedef unsigned short u16;
using bf16x8 = __attribute__((ext_vector_type(8))) short;
using f32x4  = __attribute__((ext_vector_type(4))) float;
using f4     = __attribute__((ext_vector_type(4))) float;

__device__ __forceinline__ u16 f2b(float f) {          // fp32 -> bf16 RNE
    unsigned u = __float_as_uint(f);
    return (u16)((u + 0x7fffu + ((u >> 16) & 1u)) >> 16);
}
__device__ __forceinline__ float sigm(float x) { return 1.f / (1.f + expf(-x)); }

// pack 8 consecutive fp32 (16B-aligned) into a bf16x8 MFMA fragment slice
__device__ __forceinline__ bf16x8 pack8(const float* p) {
    float4 a = *(const float4*)p, b = *(const float4*)(p + 4);
    bf16x8 r;
    r[0] = (short)f2b(a.x); r[1] = (short)f2b(a.y);
    r[2] = (short)f2b(a.z); r[3] = (short)f2b(a.w);
    r[4] = (short)f2b(b.x); r[5] = (short)f2b(b.y);
    r[6] = (short)f2b(b.z); r[7] = (short)f2b(b.w);
    return r;
}

// 64-length fp32 dot: w is global (float4-aligned), s is LDS
__device__ __forceinline__ float dot64(const float* __restrict__ w, const float* s) {
    float acc = 0.f;
    #pragma unroll
    for (int i = 0; i < 16; ++i) {
        float4 v = ((const float4*)w)[i];
        acc += v.x * s[i*4] + v.y * s[i*4+1] + v.z * s[i*4+2] + v.w * s[i*4+3];
    }
    return acc;
}

// ---------------------------------------------------------------------------
// Head, phase 1 (28 blocks x 256 thr): everything that needs only the inputs.
//   blocks 0..3  : sub = tanh(mask @ sub_W^T + sub_b) -> sub_ws, out[seed]
//   blocks 4..15 : gi0 = enc @ W_ih^T + b_ih
//   blocks 16..27: gh0 = sub @ W_hh^T + b_hh  (sub recomputed locally; the
//                  256 KB sub_W re-read is L2-resident, fp noise ~1e-7)
// ---------------------------------------------------------------------------
__global__ __launch_bounds__(256)
void k_head1(const float* __restrict__ enc, const float* __restrict__ mask,
             const float* __restrict__ W_ih, const float* __restrict__ b_ih,
             const float* __restrict__ sub_W, const float* __restrict__ sub_b,
             const float* __restrict__ W_hh, const float* __restrict__ b_hh,
             float* __restrict__ sub_ws, float* __restrict__ gi0,
             float* __restrict__ gh0, float* __restrict__ out,
             const int* __restrict__ seed_p)
{
    __shared__ float x_s[256], pA[256], sub_l[256];
    const int b = blockIdx.x, tid = threadIdx.x;
    const int t = tid >> 2, g = tid & 3;
    if (b < 4) {
        x_s[tid] = mask[tid];
        __syncthreads();
        pA[tid] = dot64(sub_W + (size_t)(b * 64 + t) * 256 + g * 64, x_s + g * 64);
        __syncthreads();
        if (tid < 64) {
            const int i = b * 64 + tid;
            float s = tanhf(pA[4*tid] + pA[4*tid+1] + pA[4*tid+2] + pA[4*tid+3] + sub_b[i]);
            sub_ws[i] = s;
            out[(size_t)seed_p[0] * 256 + i] = s;       // ent[seed] = sub
        }
    } else if (b < 16) {
        x_s[tid] = enc[tid];
        __syncthreads();
        const int j = (b - 4) * 64 + t;
        pA[tid] = dot64(W_ih + (size_t)j * 256 + g * 64, x_s + g * 64);
        __syncthreads();
        if (tid < 64) {
            const int jj = (b - 4) * 64 + tid;
            gi0[jj] = pA[4*tid] + pA[4*tid+1] + pA[4*tid+2] + pA[4*tid+3] + b_ih[jj];
        }
    } else {
        x_s[tid] = mask[tid];
        __syncthreads();
        // recompute sub[tid] locally (scalar 256-dot, L2-served)
        {
            float acc = 0.f;
            const float4* w = (const float4*)(sub_W + (size_t)tid * 256);
            #pragma unroll
            for (int i = 0; i < 64; ++i) {
                float4 v = w[i];
                acc += v.x * x_s[i*4] + v.y * x_s[i*4+1] + v.z * x_s[i*4+2] + v.w * x_s[i*4+3];
            }
            sub_l[tid] = tanhf(acc + sub_b[tid]);
        }
        __syncthreads();
        const int j = (b - 16) * 64 + t;
        pA[tid] = dot64(W_hh + (size_t)j * 256 + g * 64, sub_l + g * 64);
        __syncthreads();
        if (tid < 64) {
            const int jj = (b - 16) * 64 + tid;
            gh0[jj] = pA[4*tid] + pA[4*tid+1] + pA[4*tid+2] + pA[4*tid+3] + b_hh[jj];
        }
    }
}

// ---------------------------------------------------------------------------
// Head, phase 2 (12 blocks): r0 = GRU(gi0, gh0, sub) computed redundantly
// per block (elementwise, trivial), then gi1 = r0 @ W_ih^T + b_ih.
// ---------------------------------------------------------------------------
__global__ __launch_bounds__(256)
void k_head2(const float* __restrict__ sub_ws, const float* __restrict__ gi0,
             const float* __restrict__ gh0, const float* __restrict__ W_ih,
             const float* __restrict__ b_ih, float* __restrict__ gi1)
{
    __shared__ float r0_s[256];
    __shared__ float pA[256];
    const int tid = threadIdx.x;
    {
        float rr = sigm(gi0[tid]       + gh0[tid]);
        float zz = sigm(gi0[256 + tid] + gh0[256 + tid]);
        float nn = tanhf(gi0[512 + tid] + rr * gh0[512 + tid]);
        r0_s[tid] = (1.f - zz) * nn + zz * sub_ws[tid];
    }
    __syncthreads();
    const int t = tid >> 2, g = tid & 3;
    const int j = blockIdx.x * 64 + t;
    pA[tid] = dot64(W_ih + (size_t)j * 256 + g * 64, r0_s + g * 64);
    __syncthreads();
    if (tid < 64) {
        const int jj = blockIdx.x * 64 + tid;
        gi1[jj] = pA[4*tid] + pA[4*tid+1] + pA[4*tid+2] + pA[4*tid+3] + b_ih[jj];
    }
}

// ---------------------------------------------------------------------------
// Kernel 2 (fused): per 16-row stripe of rel_table:
//   phase A: gh MFMA (3 gates) + GRU combine -> rj (bf16) in LDS
//   phase B: obj = tanh(rj @ obj_W^T + obj_b) -> global (for the scatter)
// 256 thr = 4 waves; wave w owns col-tiles w*4..w*4+3 in both phases.
// rj never touches global memory. LDS rows padded to 264 u16 (528 B) so the
// obj A-frag ds_read_b128 is at most 2-way-aliased per 16-lane quarter.
// Numerics identical to the split version (same bf16 values, same MFMA order).
// ---------------------------------------------------------------------------
__global__ __launch_bounds__(256)
void k2_fused(const float* __restrict__ rel_table, const float* __restrict__ W_hh,
              const float* __restrict__ b_hh, const float* __restrict__ gi1,
              const float* __restrict__ obj_W, const float* __restrict__ obj_b,
              float* __restrict__ obj, int R)
{
    __shared__ u16 rj_s[16][264];
    const int tid = threadIdx.x;
    const int wv = tid >> 6, l = tid & 63;
    const int m = l & 15, q = l >> 4;
    const int tt = blockIdx.x;
    int trow = tt * 16 + m; if (trow >= R) trow = R - 1;   // clamp; stores guarded
    const float* ab = rel_table + (size_t)trow * 256 + q * 8;
    bf16x8 afr[8];
    #pragma unroll
    for (int kk = 0; kk < 8; ++kk) afr[kk] = pack8(ab + kk * 32);

    #pragma unroll
    for (int jt0 = 0; jt0 < 4; ++jt0) {
        const int jt  = wv * 4 + jt0;
        const int col = jt * 16 + m;
        const float* b0 = W_hh + (size_t)(col      ) * 256 + q * 8;
        const float* b1 = W_hh + (size_t)(col + 256) * 256 + q * 8;
        const float* b2 = W_hh + (size_t)(col + 512) * 256 + q * 8;
        f32x4 aR = {0.f,0.f,0.f,0.f}, aZ = {0.f,0.f,0.f,0.f}, aN = {0.f,0.f,0.f,0.f};
        #pragma unroll
        for (int kk = 0; kk < 8; ++kk) {
            aR = __builtin_amdgcn_mfma_f32_16x16x32_bf16(afr[kk], pack8(b0 + kk * 32), aR, 0, 0, 0);
            aZ = __builtin_amdgcn_mfma_f32_16x16x32_bf16(afr[kk], pack8(b1 + kk * 32), aZ, 0, 0, 0);
            aN = __builtin_amdgcn_mfma_f32_16x16x32_bf16(afr[kk], pack8(b2 + kk * 32), aN, 0, 0, 0);
        }
        const float gr = gi1[col], gz = gi1[256 + col], gn = gi1[512 + col];
        const float br = b_hh[col], bz = b_hh[256 + col], bn = b_hh[512 + col];
        #pragma unroll
        for (int i = 0; i < 4; ++i) {
            const int row  = tt * 16 + q * 4 + i;          // C/D: row = (l>>4)*4 + reg
            const int hrow = (row < R) ? row : (R - 1);    // keep rel_table read in-bounds
            const float h = rel_table[(size_t)hrow * 256 + col];
            const float r = sigm(gr + aR[i] + br);
            const float z = sigm(gz + aZ[i] + bz);
            const float n = tanhf(gn + r * (aN[i] + bn));
            rj_s[q * 4 + i][col] = f2b((1.f - z) * n + z * h);
        }
    }
    __syncthreads();

    #pragma unroll
    for (int jt0 = 0; jt0 < 4; ++jt0) {
        const int jt2  = wv * 4 + jt0;
        const int col2 = jt2 * 16 + m;
        const float* bb = obj_W + (size_t)col2 * 256 + q * 8;
        f32x4 acc = {0.f,0.f,0.f,0.f};
        #pragma unroll
        for (int kk = 0; kk < 8; ++kk) {
            bf16x8 a = *(const bf16x8*)&rj_s[m][kk * 32 + q * 8];
            acc = __builtin_amdgcn_mfma_f32_16x16x32_bf16(a, pack8(bb + kk * 32), acc, 0, 0, 0);
        }
        const float bias = obj_b[col2];
        #pragma unroll
        for (int i = 0; i < 4; ++i) {
            const int row = tt * 16 + q * 4 + i;
            if (row < R) obj[(size_t)row * 256 + col2] = tanhf(acc[i] + bias);
        }
    }
}

// ---------------------------------------------------------------------------
// Kernel 3: per-edge scatter (pure bandwidth). 64 lanes per 1KB row, 16B/lane.
//   out[tail_ids[e]] = state[e]==1 ? entity[origin[e]] : obj[rel_ids[e]]
// Entity rows are streamed-once from a 512 MB table -> NT load (don't evict
// the hot 1 MB obj block from L2). Output is write-once -> NT store.
// Branch is wave-uniform (one edge per wave).
// ---------------------------------------------------------------------------
__global__ __launch_bounds__(256)
void k3_scatter(const float* __restrict__ entity, const float* __restrict__ obj,
                const int* __restrict__ rel_ids, const int* __restrict__ tail_ids,
                const int* __restrict__ state, const int* __restrict__ origin,
                float* __restrict__ out, int E)
{
    const long long gidx = (long long)blockIdx.x * 256 + threadIdx.x;
    const int e = (int)(gidx >> 6);
    if (e >= E) return;
    const int c = ((int)gidx & 63) * 4;
    f4 v;
    if (state[e] == 1) {
        v = __builtin_nontemporal_load((const f4*)(entity + (size_t)origin[e] * 256 + c));
    } else {
        v = *(const f4*)(obj + (size_t)rel_ids[e] * 256 + c);
    }
    __builtin_nontemporal_store(v, (f4*)(out + (size_t)tail_ids[e] * 256 + c));
}

extern "C" void kernel_launch(void* const* d_in, const int* in_sizes, int n_in,
                              void* d_out, int out_size, void* d_ws, size_t ws_size,
                              hipStream_t stream)
{
    const float* enc       = (const float*)d_in[0];
    const float* mask      = (const float*)d_in[1];
    const float* entity    = (const float*)d_in[2];
    const float* rel_table = (const float*)d_in[3];
    const float* W_ih      = (const float*)d_in[4];
    const float* W_hh      = (const float*)d_in[5];
    const float* b_ih      = (const float*)d_in[6];
    const float* b_hh      = (const float*)d_in[7];
    const float* sub_W     = (const float*)d_in[8];
    const float* sub_b     = (const float*)d_in[9];
    const float* obj_W     = (const float*)d_in[10];
    const float* obj_b     = (const float*)d_in[11];
    const int* rel_ids     = (const int*)d_in[12];
    const int* tail_ids    = (const int*)d_in[13];
    const int* state       = (const int*)d_in[14];
    const int* origin      = (const int*)d_in[15];
    const int* seed_p      = (const int*)d_in[16];
    float* out = (float*)d_out;

    const int E = in_sizes[12];
    const int R = in_sizes[3] / 256;

    // ws layout (fp32 offsets): sub | gi0 | gh0 | gi1 | obj
    float* ws     = (float*)d_ws;
    float* sub_ws = ws;                               // 256
    float* gi0    = ws + 256;                         // 768
    float* gh0    = ws + 1024;                        // 768
    float* gi1    = ws + 1792;                        // 768
    float* obj    = ws + 2560;                        // R*256 fp32

    k_head1<<<28, 256, 0, stream>>>(enc, mask, W_ih, b_ih, sub_W, sub_b,
                                    W_hh, b_hh, sub_ws, gi0, gh0, out, seed_p);
    k_head2<<<12, 256, 0, stream>>>(sub_ws, gi0, gh0, W_ih, b_ih, gi1);

    k2_fused<<<(R + 15) / 16, 256, 0, stream>>>(rel_table, W_hh, b_hh, gi1,
                                                obj_W, obj_b, obj, R);

    const int blocks = (int)(((long long)E * 64 + 255) / 256);
    k3_scatter<<<blocks, 256, 0, stream>>>(entity, obj, rel_ids, tail_ids,
                                           state, origin, out, E);
}

// Round 3
// 710.139 us; speedup vs baseline: 1.0596x; 1.0596x over previous
//
#include <hip/hip_runtime.h>
#include <hip/hip_bf16.h>

typedef unsigned short u16;
using bf16x8 = __attribute__((ext_vector_type(8))) short;
using f32x4  = __attribute__((ext_vector_type(4))) float;
using f4     = __attribute__((ext_vector_type(4))) float;

__device__ __forceinline__ u16 f2b(float f) {          // fp32 -> bf16 RNE
    unsigned u = __float_as_uint(f);
    return (u16)((u + 0x7fffu + ((u >> 16) & 1u)) >> 16);
}
__device__ __forceinline__ float sigm(float x) { return 1.f / (1.f + expf(-x)); }

// pack 8 consecutive fp32 (16B-aligned) into a bf16x8 MFMA fragment slice
__device__ __forceinline__ bf16x8 pack8(const float* p) {
    float4 a = *(const float4*)p, b = *(const float4*)(p + 4);
    bf16x8 r;
    r[0] = (short)f2b(a.x); r[1] = (short)f2b(a.y);
    r[2] = (short)f2b(a.z); r[3] = (short)f2b(a.w);
    r[4] = (short)f2b(b.x); r[5] = (short)f2b(b.y);
    r[6] = (short)f2b(b.z); r[7] = (short)f2b(b.w);
    return r;
}

// 64-length fp32 dot: w is global (float4-aligned), s is LDS
__device__ __forceinline__ float dot64(const float* __restrict__ w, const float* s) {
    float acc = 0.f;
    #pragma unroll
    for (int i = 0; i < 16; ++i) {
        float4 v = ((const float4*)w)[i];
        acc += v.x * s[i*4] + v.y * s[i*4+1] + v.z * s[i*4+2] + v.w * s[i*4+3];
    }
    return acc;
}

// ---------------------------------------------------------------------------
// Head, phase A (16 blocks x 256 thr): input-only matvecs, weights spread
// across CUs instead of one CU streaming everything.
//   blocks 0..3 : sub = tanh(mask @ sub_W^T + sub_b) -> sub_ws, out[seed]
//   blocks 4..15: gi0 = enc @ W_ih^T + b_ih          -> gi0 ws
// Per block: 64 output dots, 4 threads per dot (64-length K-slices).
// ---------------------------------------------------------------------------
__global__ __launch_bounds__(256)
void k1a_sub_gi0(const float* __restrict__ enc, const float* __restrict__ mask,
                 const float* __restrict__ W_ih, const float* __restrict__ b_ih,
                 const float* __restrict__ sub_W, const float* __restrict__ sub_b,
                 float* __restrict__ sub_ws, float* __restrict__ gi0,
                 float* __restrict__ out, const int* __restrict__ seed_p)
{
    __shared__ float x_s[256];
    __shared__ float pA[256];
    const int b = blockIdx.x;
    const bool is_sub = (b < 4);
    const int tid = threadIdx.x;
    x_s[tid] = is_sub ? mask[tid] : enc[tid];
    __syncthreads();
    const int t = tid >> 2, g = tid & 3;
    if (is_sub) {
        const int i = b * 64 + t;                       // 0..255
        pA[tid] = dot64(sub_W + (size_t)i * 256 + g * 64, x_s + g * 64);
    } else {
        const int j = (b - 4) * 64 + t;                 // 0..767
        pA[tid] = dot64(W_ih + (size_t)j * 256 + g * 64, x_s + g * 64);
    }
    __syncthreads();
    if (tid < 64) {
        float v = pA[4*tid] + pA[4*tid+1] + pA[4*tid+2] + pA[4*tid+3];
        if (is_sub) {
            const int i = b * 64 + tid;
            float s = tanhf(v + sub_b[i]);
            sub_ws[i] = s;
            out[(size_t)seed_p[0] * 256 + i] = s;       // ent[seed] = sub
        } else {
            const int j = (b - 4) * 64 + tid;
            gi0[j] = v + b_ih[j];
        }
    }
}

// ---------------------------------------------------------------------------
// Head, phase B (12 blocks): gh0 = sub @ W_hh^T + b_hh
// ---------------------------------------------------------------------------
__global__ __launch_bounds__(256)
void k1b_gh0(const float* __restrict__ sub_ws, const float* __restrict__ W_hh,
             const float* __restrict__ b_hh, float* __restrict__ gh0)
{
    __shared__ float x_s[256];
    __shared__ float pA[256];
    const int tid = threadIdx.x;
    x_s[tid] = sub_ws[tid];
    __syncthreads();
    const int t = tid >> 2, g = tid & 3;
    const int j = blockIdx.x * 64 + t;
    pA[tid] = dot64(W_hh + (size_t)j * 256 + g * 64, x_s + g * 64);
    __syncthreads();
    if (tid < 64) {
        const int jj = blockIdx.x * 64 + tid;
        gh0[jj] = pA[4*tid] + pA[4*tid+1] + pA[4*tid+2] + pA[4*tid+3] + b_hh[jj];
    }
}

// ---------------------------------------------------------------------------
// Head, phase C (12 blocks): r0 = GRU(gi0, gh0, sub) computed redundantly
// per block (elementwise, trivial), then gi1 = r0 @ W_ih^T + b_ih.
// ---------------------------------------------------------------------------
__global__ __launch_bounds__(256)
void k1c_gi1(const float* __restrict__ sub_ws, const float* __restrict__ gi0,
             const float* __restrict__ gh0, const float* __restrict__ W_ih,
             const float* __restrict__ b_ih, float* __restrict__ gi1)
{
    __shared__ float r0_s[256];
    __shared__ float pA[256];
    const int tid = threadIdx.x;
    {
        float rr = sigm(gi0[tid]       + gh0[tid]);
        float zz = sigm(gi0[256 + tid] + gh0[256 + tid]);
        float nn = tanhf(gi0[512 + tid] + rr * gh0[512 + tid]);
        r0_s[tid] = (1.f - zz) * nn + zz * sub_ws[tid];
    }
    __syncthreads();
    const int t = tid >> 2, g = tid & 3;
    const int j = blockIdx.x * 64 + t;
    pA[tid] = dot64(W_ih + (size_t)j * 256 + g * 64, r0_s + g * 64);
    __syncthreads();
    if (tid < 64) {
        const int jj = blockIdx.x * 64 + tid;
        gi1[jj] = pA[4*tid] + pA[4*tid+1] + pA[4*tid+2] + pA[4*tid+3] + b_ih[jj];
    }
}

// ---------------------------------------------------------------------------
// Kernel 2: fused gh-MFMA + GRU combine -> rj (bf16) [R,256]
// Each block (64 thr) computes a 16x16 tile of ALL THREE gates so the
// combine runs in the epilogue on register accumulators. 1008 one-wave
// blocks: these tiny matmuls are occupancy/latency-bound, so maximize
// block count; the 0.5 MB rj round-trip through L2 is free by comparison.
// A-frag: lane holds A[m=l&15][k=q*8+j]; B-frag: B[k][n=l&15]=W[n][k].
// ---------------------------------------------------------------------------
__global__ __launch_bounds__(64)
void k2_ghcomb(const float* __restrict__ rel_table, const float* __restrict__ W_hh,
               const float* __restrict__ b_hh, const float* __restrict__ gi1,
               u16* __restrict__ rj, int R)
{
    const int l = threadIdx.x, m = l & 15, q = l >> 4;
    const int tt = blockIdx.y, jt = blockIdx.x;         // jt: 0..15 (cols)
    int trow = tt * 16 + m; if (trow >= R) trow = R - 1;  // clamp; store guarded
    const int col = jt * 16 + m;
    const float* ab = rel_table + (size_t)trow * 256 + q * 8;
    const float* b0 = W_hh + (size_t)(col      ) * 256 + q * 8;
    const float* b1 = W_hh + (size_t)(col + 256) * 256 + q * 8;
    const float* b2 = W_hh + (size_t)(col + 512) * 256 + q * 8;
    f32x4 aR = {0.f,0.f,0.f,0.f}, aZ = {0.f,0.f,0.f,0.f}, aN = {0.f,0.f,0.f,0.f};
    #pragma unroll
    for (int kk = 0; kk < 8; ++kk) {
        bf16x8 a = pack8(ab + kk * 32);
        aR = __builtin_amdgcn_mfma_f32_16x16x32_bf16(a, pack8(b0 + kk * 32), aR, 0, 0, 0);
        aZ = __builtin_amdgcn_mfma_f32_16x16x32_bf16(a, pack8(b1 + kk * 32), aZ, 0, 0, 0);
        aN = __builtin_amdgcn_mfma_f32_16x16x32_bf16(a, pack8(b2 + kk * 32), aN, 0, 0, 0);
    }
    const float gr = gi1[col], gz = gi1[256 + col], gn = gi1[512 + col];
    const float br = b_hh[col], bz = b_hh[256 + col], bn = b_hh[512 + col];
    #pragma unroll
    for (int i = 0; i < 4; ++i) {
        const int row = tt * 16 + q * 4 + i;            // C/D: row = (l>>4)*4 + reg
        if (row < R) {
            const float h = rel_table[(size_t)row * 256 + col];
            const float r = sigm(gr + aR[i] + br);
            const float z = sigm(gz + aZ[i] + bz);
            const float n = tanhf(gn + r * (aN[i] + bn));
            rj[(size_t)row * 256 + col] = f2b((1.f - z) * n + z * h);
        }
    }
}

// ---------------------------------------------------------------------------
// Kernel 2c: obj[R,256] = tanh(rj @ obj_W^T + obj_b)  (MFMA, fp32 out)
// ---------------------------------------------------------------------------
__global__ __launch_bounds__(64)
void k2_obj(const u16* __restrict__ rj, const float* __restrict__ obj_W,
            const float* __restrict__ obj_b, float* __restrict__ obj, int R)
{
    const int l = threadIdx.x, m = l & 15, q = l >> 4;
    const int tt = blockIdx.y, jt = blockIdx.x;
    int trow = tt * 16 + m; if (trow >= R) trow = R - 1;
    const u16* ab = rj + (size_t)trow * 256 + q * 8;
    const float* bb = obj_W + (size_t)(jt * 16 + m) * 256 + q * 8;
    f32x4 acc = {0.f, 0.f, 0.f, 0.f};
    #pragma unroll
    for (int kk = 0; kk < 8; ++kk) {
        bf16x8 a = *(const bf16x8*)(ab + kk * 32);   // rj already bf16
        bf16x8 b = pack8(bb + kk * 32);
        acc = __builtin_amdgcn_mfma_f32_16x16x32_bf16(a, b, acc, 0, 0, 0);
    }
    const int col = jt * 16 + m;
    const float bias = obj_b[col];
    #pragma unroll
    for (int i = 0; i < 4; ++i) {
        const int row = tt * 16 + q * 4 + i;
        if (row < R) obj[(size_t)row * 256 + col] = tanhf(acc[i] + bias);
    }
}

// ---------------------------------------------------------------------------
// Kernel 3: per-edge scatter (pure bandwidth). 64 lanes per 1KB row, 16B/lane.
//   out[tail_ids[e]] = state[e]==1 ? entity[origin[e]] : obj[rel_ids[e]]
// e is wave-uniform (64 lanes per edge): readfirstlane makes it scalar so
// the 4 index reads become s_loads and the state branch is a scalar branch.
// Output is write-once/never-read -> non-temporal stores keep L2 for the
// entity/obj gathers.
// ---------------------------------------------------------------------------
__global__ __launch_bounds__(256)
void k3_scatter(const float* __restrict__ entity, const float* __restrict__ obj,
                const int* __restrict__ rel_ids, const int* __restrict__ tail_ids,
                const int* __restrict__ state, const int* __restrict__ origin,
                float* __restrict__ out, int E)
{
    const long long gidx = (long long)blockIdx.x * 256 + threadIdx.x;
    int e = (int)(gidx >> 6);
    if (e >= E) return;                     // wave-uniform guard
    e = __builtin_amdgcn_readfirstlane(e);  // provably uniform across the wave
    const int c = (threadIdx.x & 63) * 4;
    const float* src = (state[e] == 1) ? entity + (size_t)origin[e] * 256
                                       : obj + (size_t)rel_ids[e] * 256;
    f4 v = *(const f4*)(src + c);
    __builtin_nontemporal_store(v, (f4*)(out + (size_t)tail_ids[e] * 256 + c));
}

extern "C" void kernel_launch(void* const* d_in, const int* in_sizes, int n_in,
                              void* d_out, int out_size, void* d_ws, size_t ws_size,
                              hipStream_t stream)
{
    const float* enc       = (const float*)d_in[0];
    const float* mask      = (const float*)d_in[1];
    const float* entity    = (const float*)d_in[2];
    const float* rel_table = (const float*)d_in[3];
    const float* W_ih      = (const float*)d_in[4];
    const float* W_hh      = (const float*)d_in[5];
    const float* b_ih      = (const float*)d_in[6];
    const float* b_hh      = (const float*)d_in[7];
    const float* sub_W     = (const float*)d_in[8];
    const float* sub_b     = (const float*)d_in[9];
    const float* obj_W     = (const float*)d_in[10];
    const float* obj_b     = (const float*)d_in[11];
    const int* rel_ids     = (const int*)d_in[12];
    const int* tail_ids    = (const int*)d_in[13];
    const int* state       = (const int*)d_in[14];
    const int* origin      = (const int*)d_in[15];
    const int* seed_p      = (const int*)d_in[16];
    float* out = (float*)d_out;

    const int E = in_sizes[12];
    const int R = in_sizes[3] / 256;

    // ws layout (fp32 offsets): sub | gi0 | gh0 | gi1 | rj (bf16) | obj (fp32)
    float* ws     = (float*)d_ws;
    float* sub_ws = ws;                               // 256
    float* gi0    = ws + 256;                         // 768
    float* gh0    = ws + 1024;                        // 768
    float* gi1    = ws + 1792;                        // 768
    u16*   rj     = (u16*)(ws + 2560);                // R*256 bf16
    float* obj    = (float*)((char*)rj + (size_t)R * 256 * 2);  // R*256 fp32

    k1a_sub_gi0<<<16, 256, 0, stream>>>(enc, mask, W_ih, b_ih, sub_W, sub_b,
                                        sub_ws, gi0, out, seed_p);
    k1b_gh0<<<12, 256, 0, stream>>>(sub_ws, W_hh, b_hh, gh0);
    k1c_gi1<<<12, 256, 0, stream>>>(sub_ws, gi0, gh0, W_ih, b_ih, gi1);

    dim3 g_ghc(16, (R + 15) / 16);
    k2_ghcomb<<<g_ghc, 64, 0, stream>>>(rel_table, W_hh, b_hh, gi1, rj, R);
    dim3 g_obj(16, (R + 15) / 16);
    k2_obj<<<g_obj, 64, 0, stream>>>(rj, obj_W, obj_b, obj, R);

    const int blocks = (int)(((long long)E * 64 + 255) / 256);
    k3_scatter<<<blocks, 256, 0, stream>>>(entity, obj, rel_ids, tail_ids,
                                           state, origin, out, E);
}